// Round 1
// baseline (1788.838 us; speedup 1.0000x reference)
//
#include <hip/hip_runtime.h>
#include <math.h>

#define N_LEVELS 16
#define MAX_SIZE (1u << 19)   // 2^19 entries per level slab in `tables`

struct Params {
    float res[N_LEVELS];
    unsigned int mask[N_LEVELS];
};

// One thread per (point, level): t = n*16 + l.
// - out is [N, 32] f32 = [N*16] float2; thread t writes out[t] -> perfectly coalesced.
// - 8 independent 8B gathers per thread; low VGPR -> high occupancy for latency hiding.
__global__ __launch_bounds__(256) void hashgrid_kernel(
    const float* __restrict__ x,
    const float* __restrict__ tables,
    float2* __restrict__ out,
    Params p, int total)
{
    int t = blockIdx.x * 256 + threadIdx.x;
    if (t >= total) return;
    int l = t & 15;
    int n = t >> 4;

    float res = p.res[l];
    unsigned int mask = p.mask[l];
    const float2* __restrict__ tab =
        reinterpret_cast<const float2*>(tables) + (size_t)l * MAX_SIZE;

    float px = x[n * 3 + 0];
    float py = x[n * 3 + 1];
    float pz = x[n * 3 + 2];

    // f32 semantics identical to reference: xs = x*res (f32), xi = floor, xf = xs - xi
    float xs = px * res, ys = py * res, zs = pz * res;
    float fxi = floorf(xs), fyi = floorf(ys), fzi = floorf(zs);
    float wx1 = xs - fxi, wy1 = ys - fyi, wz1 = zs - fzi;   // upper-corner weights
    float wx0 = 1.0f - wx1, wy0 = 1.0f - wy1, wz0 = 1.0f - wz1;

    unsigned int ix = (unsigned int)fxi;
    unsigned int iy = (unsigned int)fyi;
    unsigned int iz = (unsigned int)fzi;

    const unsigned int P2 = 2654435761u, P3 = 805459861u;
    unsigned int hx0 = ix;       unsigned int hx1 = ix + 1u;
    unsigned int hy0 = iy * P2;  unsigned int hy1 = hy0 + P2;   // (iy+1)*P2 mod 2^32
    unsigned int hz0 = iz * P3;  unsigned int hz1 = hz0 + P3;

    // Corner c: bit0->x upper, bit1->y upper, bit2->z upper (matches BIN_MASK).
    unsigned int hidx[8];
    float w[8];
#pragma unroll
    for (int c = 0; c < 8; ++c) {
        unsigned int hh = ((c & 1) ? hx1 : hx0)
                        ^ ((c & 2) ? hy1 : hy0)
                        ^ ((c & 4) ? hz1 : hz0);
        hidx[c] = hh & mask;
        // reference order: ((wx*wy)*wz)
        w[c] = (((c & 1) ? wx1 : wx0) * ((c & 2) ? wy1 : wy0)) * ((c & 4) ? wz1 : wz0);
    }

    // Issue all 8 gathers before use -> 8 outstanding loads per thread.
    float2 v[8];
#pragma unroll
    for (int c = 0; c < 8; ++c) v[c] = tab[hidx[c]];

    float accx = 0.0f, accy = 0.0f;
#pragma unroll
    for (int c = 0; c < 8; ++c) {   // sequential sum order matches reference axis sum
        accx += v[c].x * w[c];
        accy += v[c].y * w[c];
    }

    out[t] = make_float2(accx, accy);
}

extern "C" void kernel_launch(void* const* d_in, const int* in_sizes, int n_in,
                              void* d_out, int out_size, void* d_ws, size_t ws_size,
                              hipStream_t stream) {
    const float* x      = (const float*)d_in[0];
    const float* tables = (const float*)d_in[1];
    float2* out         = (float2*)d_out;

    int N = in_sizes[0] / 3;

    // Replicate Python's level-constant computation bit-exactly with libm doubles:
    //   b = exp((log(512) - log(16)) / 15); res_l = floor(16 * b**l)
    //   size_l = next_pow2(min(res_l^3, 2^19))
    Params p;
    double b = exp((log(512.0) - log(16.0)) / 15.0);
    for (int l = 0; l < N_LEVELS; ++l) {
        double r = floor(16.0 * pow(b, (double)l));
        long long res = (long long)r;
        long long cube = res * res * res;
        long long sz = cube < (long long)(1u << 19) ? cube : (long long)(1u << 19);
        unsigned int pw = 1;
        while ((long long)pw < sz) pw <<= 1;
        p.res[l]  = (float)r;
        p.mask[l] = pw - 1u;
    }

    int total = N * N_LEVELS;
    int blocks = (total + 255) / 256;
    hashgrid_kernel<<<blocks, 256, 0, stream>>>(x, tables, out, p, total);
}